// Round 6
// baseline (1245.021 us; speedup 1.0000x reference)
//
#include <hip/hip_runtime.h>
#include <hip/hip_fp16.h>

#define SLOPE 0.2f
#define NEG_INF -3.4e38f

__device__ __forceinline__ float lrelu(float v) { return v >= 0.f ? v : SLOPE * v; }

__device__ __forceinline__ unsigned pack2(float a, float b) {
    __half2 h = __floats2half2_rn(a, b);
    return *reinterpret_cast<unsigned*>(&h);
}
__device__ __forceinline__ float4 h4tof4(uint2 u) {
    __half2 a = *reinterpret_cast<__half2*>(&u.x);
    __half2 b = *reinterpret_cast<__half2*>(&u.y);
    float2 fa = __half22float2(a), fb = __half22float2(b);
    return make_float4(fa.x, fa.y, fb.x, fb.y);
}

// ============================================================================
// xp = x @ W (K -> 128 = 2 heads * 64) fused with attention dots.
// Thread = (node, head): 64 fp32 accumulators, W in LDS, in-register att dots,
// fp16 xp output (128 B coalesced per thread). No cross-lane ops at all.
// ============================================================================
template <int K>
__global__ __launch_bounds__(256, 3)
void k_xp(const float* __restrict__ x, const float* __restrict__ W,
          const float* __restrict__ as_, const float* __restrict__ ad_,
          __half* __restrict__ xph, float* __restrict__ asrc,
          float* __restrict__ adst, int N) {
    __shared__ float4 wl[K * 32];     // W [K][128]
    __shared__ float4 avl[64];        // as_ (32) then ad_ (32)
    for (int i = threadIdx.x; i < K * 32; i += 256) wl[i] = ((const float4*)W)[i];
    for (int i = threadIdx.x; i < 64; i += 256)
        avl[i] = (i < 32) ? ((const float4*)as_)[i] : ((const float4*)ad_)[i - 32];
    __syncthreads();

    int gtid = blockIdx.x * 256 + threadIdx.x;
    int nt = gridDim.x * 256;
    for (int idx = gtid; idx < 2 * N; idx += nt) {
        int n = idx >> 1, h = idx & 1;
        float4 m[16];
        #pragma unroll
        for (int j = 0; j < 16; ++j) m[j] = make_float4(0.f, 0.f, 0.f, 0.f);

        if constexpr (K % 4 == 0) {
            const float4* xr = (const float4*)(x + (size_t)n * K);
            #pragma unroll
            for (int k4 = 0; k4 < K / 4; ++k4) {
                float4 hv = xr[k4];
                const float4* w0 = &wl[(k4 * 4 + 0) * 32 + h * 16];
                const float4* w1 = &wl[(k4 * 4 + 1) * 32 + h * 16];
                const float4* w2 = &wl[(k4 * 4 + 2) * 32 + h * 16];
                const float4* w3 = &wl[(k4 * 4 + 3) * 32 + h * 16];
                #pragma unroll
                for (int j = 0; j < 16; ++j) {
                    float4 a = w0[j], bq = w1[j], cq = w2[j], dq = w3[j];
                    m[j].x += hv.x * a.x + hv.y * bq.x + hv.z * cq.x + hv.w * dq.x;
                    m[j].y += hv.x * a.y + hv.y * bq.y + hv.z * cq.y + hv.w * dq.y;
                    m[j].z += hv.x * a.z + hv.y * bq.z + hv.z * cq.z + hv.w * dq.z;
                    m[j].w += hv.x * a.w + hv.y * bq.w + hv.z * cq.w + hv.w * dq.w;
                }
            }
        } else {
            #pragma unroll
            for (int k = 0; k < K; ++k) {
                float hv = x[(size_t)n * K + k];
                const float4* wr = &wl[k * 32 + h * 16];
                #pragma unroll
                for (int j = 0; j < 16; ++j) {
                    float4 w4 = wr[j];
                    m[j].x += hv * w4.x; m[j].y += hv * w4.y;
                    m[j].z += hv * w4.z; m[j].w += hv * w4.w;
                }
            }
        }

        // attention dots (fp32, in-register)
        float ps = 0.f, pd = 0.f;
        const float4* asr = &avl[h * 16];
        const float4* adr = &avl[32 + h * 16];
        #pragma unroll
        for (int j = 0; j < 16; ++j) {
            float4 a = asr[j], d = adr[j];
            ps += m[j].x * a.x + m[j].y * a.y + m[j].z * a.z + m[j].w * a.w;
            pd += m[j].x * d.x + m[j].y * d.y + m[j].z * d.z + m[j].w * d.w;
        }

        // pack fp16 and store 128 B
        uint4* dst = (uint4*)(xph + (size_t)n * 128 + h * 64);
        #pragma unroll
        for (int q = 0; q < 8; ++q) {
            uint4 u;
            u.x = pack2(m[2 * q].x, m[2 * q].y);
            u.y = pack2(m[2 * q].z, m[2 * q].w);
            u.z = pack2(m[2 * q + 1].x, m[2 * q + 1].y);
            u.w = pack2(m[2 * q + 1].z, m[2 * q + 1].w);
            dst[q] = u;
        }
        asrc[idx] = ps;
        adst[idx] = pd;
    }
}

// ============================================================================
// CSR build: histogram -> exclusive scan -> scatter (counting sort by dst)
// ============================================================================
__global__ void k_hist(const int* __restrict__ dst, int* __restrict__ deg, int E) {
    for (int e = blockIdx.x * blockDim.x + threadIdx.x; e < E; e += gridDim.x * blockDim.x)
        atomicAdd(&deg[dst[e]], 1);
}

__global__ void k_scan_partial(const int* __restrict__ deg, int* __restrict__ partial, int N) {
    int b = blockIdx.x, t = threadIdx.x;
    int base = b * 1024 + t * 4;
    int s = 0;
    for (int i = 0; i < 4; ++i) { int idx = base + i; if (idx < N) s += deg[idx]; }
    __shared__ int sh[256];
    sh[t] = s; __syncthreads();
    for (int off = 128; off > 0; off >>= 1) { if (t < off) sh[t] += sh[t + off]; __syncthreads(); }
    if (t == 0) partial[b] = sh[0];
}

__global__ void k_scan_partials(int* __restrict__ partial, int nb) {
    __shared__ int sh[256];
    __shared__ int carry;
    int t = threadIdx.x;
    if (t == 0) carry = 0;
    __syncthreads();
    for (int base = 0; base < nb; base += 256) {
        int idx = base + t;
        int orig = (idx < nb) ? partial[idx] : 0;
        sh[t] = orig; __syncthreads();
        for (int off = 1; off < 256; off <<= 1) {
            int v = (t >= off) ? sh[t - off] : 0;
            __syncthreads();
            sh[t] += v;
            __syncthreads();
        }
        if (idx < nb) partial[idx] = carry + sh[t] - orig;
        __syncthreads();
        if (t == 0) carry += sh[255];
        __syncthreads();
    }
}

__global__ void k_scan_final(const int* __restrict__ deg, const int* __restrict__ partial,
                             int* __restrict__ rowptr, int N, int E) {
    int b = blockIdx.x, t = threadIdx.x;
    int base = b * 1024 + t * 4;
    int local[4]; int s = 0;
    for (int i = 0; i < 4; ++i) { int idx = base + i; local[i] = (idx < N) ? deg[idx] : 0; s += local[i]; }
    __shared__ int sh[256];
    int orig = s;
    sh[t] = s; __syncthreads();
    for (int off = 1; off < 256; off <<= 1) {
        int v = (t >= off) ? sh[t - off] : 0;
        __syncthreads();
        sh[t] += v;
        __syncthreads();
    }
    int run = partial[b] + sh[t] - orig;
    for (int i = 0; i < 4; ++i) {
        int idx = base + i;
        if (idx < N) rowptr[idx] = run;
        run += local[i];
    }
    if (b == 0 && t == 0) rowptr[N] = E;
}

__global__ void k_scatter(const int* __restrict__ src, const int* __restrict__ dst,
                          const int* __restrict__ rowptr, int* __restrict__ cur,
                          int* __restrict__ csr_src, int E) {
    for (int e = blockIdx.x * blockDim.x + threadIdx.x; e < E; e += gridDim.x * blockDim.x) {
        int d = dst[e];
        int pos = atomicAdd(&cur[d], 1);
        csr_src[rowptr[d] + pos] = src[e];
    }
}

// ============================================================================
// Per-node softmax -> alpha planes. Persistent wave-pair per node (wave=head).
// ============================================================================
__global__ void k_node_alpha(const int* __restrict__ rowptr, const int* __restrict__ csr_src,
                             const float* __restrict__ asrc, const float* __restrict__ adst,
                             float* __restrict__ alpha, float* __restrict__ aself,
                             int N, int E) {
    int tid = blockIdx.x * blockDim.x + threadIdx.x;
    int lane = threadIdx.x & 63;
    int h = (threadIdx.x >> 6) & 1;
    int pair = tid >> 7;
    int npairs = (gridDim.x * blockDim.x) >> 7;

    for (int n = pair; n < N; n += npairs) {
        int rs = rowptr[n], re = rowptr[n + 1], cnt = re - rs;
        float a_dst = adst[n * 2 + h];
        float v_self = lrelu(asrc[n * 2 + h] + a_dst);

        if (cnt <= 64) {
            float v = NEG_INF;
            if (lane < cnt) {
                int s = csr_src[rs + lane];
                v = lrelu(asrc[s * 2 + h] + a_dst);
            }
            float m = fmaxf(v, v_self);
            for (int off = 32; off > 0; off >>= 1) m = fmaxf(m, __shfl_xor(m, off, 64));
            float ex = (lane < cnt) ? __expf(v - m) : 0.f;
            float exs = __expf(v_self - m);
            float den = ex + (lane == 0 ? exs : 0.f);
            for (int off = 32; off > 0; off >>= 1) den += __shfl_xor(den, off, 64);
            float inv = 1.f / (den + 1e-16f);
            if (lane < cnt) alpha[(size_t)h * E + rs + lane] = ex * inv;
            if (lane == 0) aself[(size_t)h * N + n] = exs * inv;
        } else {
            float m = v_self;
            for (int e = rs + lane; e < re; e += 64) {
                int s = csr_src[e];
                m = fmaxf(m, lrelu(asrc[s * 2 + h] + a_dst));
            }
            for (int off = 32; off > 0; off >>= 1) m = fmaxf(m, __shfl_xor(m, off, 64));
            float den = (lane == 0) ? __expf(v_self - m) : 0.f;
            for (int e = rs + lane; e < re; e += 64) {
                int s = csr_src[e];
                den += __expf(lrelu(asrc[s * 2 + h] + a_dst) - m);
            }
            for (int off = 32; off > 0; off >>= 1) den += __shfl_xor(den, off, 64);
            float inv = 1.f / (den + 1e-16f);
            for (int e = rs + lane; e < re; e += 64) {
                int s = csr_src[e];
                alpha[(size_t)h * E + e] = __expf(lrelu(asrc[s * 2 + h] + a_dst) - m) * inv;
            }
            if (lane == 0) aself[(size_t)h * N + n] = __expf(v_self - m) * inv;
        }
    }
}

// ============================================================================
// Weighted gather (fp16 xp): one wave per node, 4 lane-groups of 16:
// group g -> head (g&1), edge offset (g>>1). 2x unrolled. 8 B/lane loads.
// ============================================================================
__global__ void k_gather(const int* __restrict__ rowptr, const int* __restrict__ csr_src,
                         const float* __restrict__ alpha, const float* __restrict__ aself,
                         const __half* __restrict__ xph, const float* __restrict__ b,
                         float* __restrict__ hout, int N, int E) {
    int tid = blockIdx.x * blockDim.x + threadIdx.x;
    int lane = threadIdx.x & 63;
    int wid = tid >> 6;
    int nw = (gridDim.x * blockDim.x) >> 6;
    int g = lane >> 4, c4 = lane & 15;
    int h = g & 1, eo = g >> 1;
    const uint2* xp2 = (const uint2*)xph;   // row = 32 uint2 (16 per head)
    float4 bb = ((const float4*)b)[c4];

    for (int n = wid; n < N; n += nw) {
        int rs = rowptr[n], re = rowptr[n + 1];
        float4 acc = make_float4(0.f, 0.f, 0.f, 0.f);
        if (eo == 0) {                       // self contribution on groups 0,1
            float a0 = aself[(size_t)h * N + n];
            float4 v = h4tof4(xp2[(size_t)n * 32 + h * 16 + c4]);
            acc.x = a0 * v.x; acc.y = a0 * v.y; acc.z = a0 * v.z; acc.w = a0 * v.w;
        }
        for (int e0 = rs; e0 < re; e0 += 4) {
            int ea = e0 + eo, eb = e0 + 2 + eo;
            bool va = ea < re, vb = eb < re;
            int sa = va ? csr_src[ea] : n;
            int sb = vb ? csr_src[eb] : n;
            float aa = va ? alpha[(size_t)h * E + ea] : 0.f;
            float ab = vb ? alpha[(size_t)h * E + eb] : 0.f;
            float4 v1 = h4tof4(xp2[(size_t)sa * 32 + h * 16 + c4]);
            float4 v2 = h4tof4(xp2[(size_t)sb * 32 + h * 16 + c4]);
            acc.x += aa * v1.x + ab * v2.x;
            acc.y += aa * v1.y + ab * v2.y;
            acc.z += aa * v1.z + ab * v2.z;
            acc.w += aa * v1.w + ab * v2.w;
        }
        acc.x += __shfl_xor(acc.x, 32, 64);
        acc.y += __shfl_xor(acc.y, 32, 64);
        acc.z += __shfl_xor(acc.z, 32, 64);
        acc.w += __shfl_xor(acc.w, 32, 64);
        acc.x += __shfl_xor(acc.x, 16, 64);
        acc.y += __shfl_xor(acc.y, 16, 64);
        acc.z += __shfl_xor(acc.z, 16, 64);
        acc.w += __shfl_xor(acc.w, 16, 64);
        if (g == 0) {
            float4 r;
            r.x = fmaxf(acc.x * 0.5f + bb.x, 0.f);
            r.y = fmaxf(acc.y * 0.5f + bb.y, 0.f);
            r.z = fmaxf(acc.z * 0.5f + bb.z, 0.f);
            r.w = fmaxf(acc.w * 0.5f + bb.w, 0.f);
            ((float4*)hout)[(size_t)n * 16 + c4] = r;
        }
    }
}

// climber embed: relu(climber @ Wc + bc), [G,64]
__global__ void k_climber(const float* __restrict__ climber, const float* __restrict__ Wc,
                          const float* __restrict__ bc, float* __restrict__ cemb, int g64) {
    int i = blockIdx.x * blockDim.x + threadIdx.x;
    if (i >= g64) return;
    int g = i >> 6, c = i & 63;
    float acc = bc[c];
    for (int k = 0; k < 4; ++k) acc += climber[g * 4 + k] * Wc[k * 64 + c];
    cemb[i] = acc > 0.f ? acc : 0.f;
}

// cpre[g] = cemb[g] @ Wm1[64:128] + bm1   (no relu; folded into k_final)
__global__ __launch_bounds__(256, 3)
void k_cpre(const float* __restrict__ cemb, const float* __restrict__ Wm1,
            const float* __restrict__ bm1, float* __restrict__ cpre, int G) {
    __shared__ float4 wl[1024];       // Wm1 rows 64..127
    for (int i = threadIdx.x; i < 1024; i += 256) wl[i] = ((const float4*)Wm1)[1024 + i];
    __syncthreads();
    const float4* c4p = (const float4*)cemb;
    const float4* bp = (const float4*)bm1;
    int gtid = blockIdx.x * 256 + threadIdx.x;
    int nt = gridDim.x * 256;
    for (int gph = gtid; gph < G; gph += nt) {
        float4 m[16];
        #pragma unroll
        for (int j = 0; j < 16; ++j) m[j] = bp[j];
        #pragma unroll
        for (int k4 = 0; k4 < 16; ++k4) {
            float4 hv = c4p[(size_t)gph * 16 + k4];
            const float4* w0 = &wl[(k4 * 4 + 0) * 16];
            const float4* w1 = &wl[(k4 * 4 + 1) * 16];
            const float4* w2 = &wl[(k4 * 4 + 2) * 16];
            const float4* w3 = &wl[(k4 * 4 + 3) * 16];
            #pragma unroll
            for (int j = 0; j < 16; ++j) {
                float4 a = w0[j], bq = w1[j], cq = w2[j], dq = w3[j];
                m[j].x += hv.x * a.x + hv.y * bq.x + hv.z * cq.x + hv.w * dq.x;
                m[j].y += hv.x * a.y + hv.y * bq.y + hv.z * cq.y + hv.w * dq.y;
                m[j].z += hv.x * a.z + hv.y * bq.z + hv.z * cq.z + hv.w * dq.z;
                m[j].w += hv.x * a.w + hv.y * bq.w + hv.z * cq.w + hv.w * dq.w;
            }
        }
        float4* dst = (float4*)cpre + (size_t)gph * 16;
        #pragma unroll
        for (int j = 0; j < 16; ++j) dst[j] = m[j];
    }
}

// ============================================================================
// Final MLP: thread per node. m = h2[n]@Wm1_a + cpre[batch[n]]; relu; @Wm2+bm2.
// Wm1_a + Wm2 in LDS (broadcast reads). Zero cross-lane ops.
// ============================================================================
__global__ __launch_bounds__(256, 3)
void k_final(const float* __restrict__ h2, const float* __restrict__ cpre,
             const int* __restrict__ batch, const float* __restrict__ Wm1,
             const float* __restrict__ Wm2, const float* __restrict__ bm2,
             float* __restrict__ out, int N) {
    __shared__ float4 wl[1024];       // Wm1 rows 0..63
    __shared__ float4 w2l[64];        // Wm2 [64][4]
    for (int i = threadIdx.x; i < 1024; i += 256) wl[i] = ((const float4*)Wm1)[i];
    for (int i = threadIdx.x; i < 64; i += 256) w2l[i] = ((const float4*)Wm2)[i];
    __syncthreads();
    const float4* h24 = (const float4*)h2;
    const float4* cp4 = (const float4*)cpre;
    float4 bm2v = *((const float4*)bm2);
    int gtid = blockIdx.x * 256 + threadIdx.x;
    int nt = gridDim.x * 256;
    for (int n = gtid; n < N; n += nt) {
        int b = batch[n];
        float4 m[16];
        #pragma unroll
        for (int j = 0; j < 16; ++j) m[j] = cp4[(size_t)b * 16 + j];
        #pragma unroll
        for (int k4 = 0; k4 < 16; ++k4) {
            float4 hv = h24[(size_t)n * 16 + k4];
            const float4* w0 = &wl[(k4 * 4 + 0) * 16];
            const float4* w1 = &wl[(k4 * 4 + 1) * 16];
            const float4* w2 = &wl[(k4 * 4 + 2) * 16];
            const float4* w3 = &wl[(k4 * 4 + 3) * 16];
            #pragma unroll
            for (int j = 0; j < 16; ++j) {
                float4 a = w0[j], bq = w1[j], cq = w2[j], dq = w3[j];
                m[j].x += hv.x * a.x + hv.y * bq.x + hv.z * cq.x + hv.w * dq.x;
                m[j].y += hv.x * a.y + hv.y * bq.y + hv.z * cq.y + hv.w * dq.y;
                m[j].z += hv.x * a.z + hv.y * bq.z + hv.z * cq.z + hv.w * dq.z;
                m[j].w += hv.x * a.w + hv.y * bq.w + hv.z * cq.w + hv.w * dq.w;
            }
        }
        float4 o = bm2v;
        #pragma unroll
        for (int j = 0; j < 16; ++j) {
            float mv; float4 w;
            mv = fmaxf(m[j].x, 0.f); w = w2l[j * 4 + 0];
            o.x += mv * w.x; o.y += mv * w.y; o.z += mv * w.z; o.w += mv * w.w;
            mv = fmaxf(m[j].y, 0.f); w = w2l[j * 4 + 1];
            o.x += mv * w.x; o.y += mv * w.y; o.z += mv * w.z; o.w += mv * w.w;
            mv = fmaxf(m[j].z, 0.f); w = w2l[j * 4 + 2];
            o.x += mv * w.x; o.y += mv * w.y; o.z += mv * w.z; o.w += mv * w.w;
            mv = fmaxf(m[j].w, 0.f); w = w2l[j * 4 + 3];
            o.x += mv * w.x; o.y += mv * w.y; o.z += mv * w.z; o.w += mv * w.w;
        }
        ((float4*)out)[n] = o;
    }
}

extern "C" void kernel_launch(void* const* d_in, const int* in_sizes, int n_in,
                              void* d_out, int out_size, void* d_ws, size_t ws_size,
                              hipStream_t stream) {
    const float* x       = (const float*)d_in[0];
    const int*   ei      = (const int*)  d_in[1];
    const int*   batch   = (const int*)  d_in[2];
    const float* climber = (const float*)d_in[3];
    const float* W1  = (const float*)d_in[4];
    const float* as1 = (const float*)d_in[5];
    const float* ad1 = (const float*)d_in[6];
    const float* b1  = (const float*)d_in[7];
    const float* W2  = (const float*)d_in[8];
    const float* as2 = (const float*)d_in[9];
    const float* ad2 = (const float*)d_in[10];
    const float* b2  = (const float*)d_in[11];
    const float* Wc  = (const float*)d_in[12];
    const float* bc  = (const float*)d_in[13];
    const float* Wm1 = (const float*)d_in[14];
    const float* bm1 = (const float*)d_in[15];
    const float* Wm2 = (const float*)d_in[16];
    const float* bm2 = (const float*)d_in[17];

    const int N  = in_sizes[0] / 6;
    const int E  = in_sizes[1] / 2;
    const int G  = in_sizes[3] / 4;

    const int* srcI = ei;
    const int* dstI = ei + E;

    // ---------------- workspace carve ----------------
    char* base = (char*)d_ws;
    size_t off = 0;
    auto carve = [&](size_t bytes) { void* p = base + off; off += (bytes + 255) & ~size_t(255); return p; };
    __half* xph   = (__half*)carve((size_t)N * 128 * 2);
    float* hbuf   = (float*)carve((size_t)N * 64 * 4);
    float* asrc   = (float*)carve((size_t)N * 2 * 4);
    float* adst   = (float*)carve((size_t)N * 2 * 4);
    float* cemb   = (float*)carve((size_t)G * 64 * 4);
    float* cpre   = (float*)carve((size_t)G * 64 * 4);
    int*   deg    = (int*)  carve((size_t)N * 4);
    int*   rowptr = (int*)  carve((size_t)(N + 1) * 4);
    int*   cur    = (int*)  carve((size_t)N * 4);
    int*   partial= (int*)  carve(4096 * 4);
    int*   csr_src= (int*)  carve((size_t)E * 4);
    float* alpha  = (float*)carve((size_t)E * 2 * 4);
    float* aself  = (float*)carve((size_t)N * 2 * 4);

    const int tpb = 256;
    const int nScanBlk = (N + 1023) / 1024;
    const int PG = 2048;                          // persistent grid for alpha/gather
    const int bXp = (2 * N + tpb - 1) / tpb;      // thread per (node, head)
    const int bFin = (N + tpb - 1) / tpb;         // thread per node

    // ---------------- CSR build (shared by both layers) ----------------
    hipMemsetAsync(deg, 0, (size_t)N * 4, stream);
    hipMemsetAsync(cur, 0, (size_t)N * 4, stream);
    k_hist<<<1024, tpb, 0, stream>>>(dstI, deg, E);
    k_scan_partial<<<nScanBlk, tpb, 0, stream>>>(deg, partial, N);
    k_scan_partials<<<1, tpb, 0, stream>>>(partial, nScanBlk);
    k_scan_final<<<nScanBlk, tpb, 0, stream>>>(deg, partial, rowptr, N, E);
    k_scatter<<<1024, tpb, 0, stream>>>(srcI, dstI, rowptr, cur, csr_src, E);

    // ---------------- layer 1 ----------------
    k_xp<6><<<bXp, tpb, 0, stream>>>(x, W1, as1, ad1, xph, asrc, adst, N);
    k_node_alpha<<<PG, tpb, 0, stream>>>(rowptr, csr_src, asrc, adst, alpha, aself, N, E);
    k_gather<<<PG, tpb, 0, stream>>>(rowptr, csr_src, alpha, aself, xph, b1, hbuf, N, E);

    // ---------------- layer 2 ----------------
    k_xp<64><<<bXp, tpb, 0, stream>>>(hbuf, W2, as2, ad2, xph, asrc, adst, N);
    k_node_alpha<<<PG, tpb, 0, stream>>>(rowptr, csr_src, asrc, adst, alpha, aself, N, E);
    k_gather<<<PG, tpb, 0, stream>>>(rowptr, csr_src, alpha, aself, xph, b2, hbuf, N, E);

    // ---------------- classifier ----------------
    k_climber<<<(G * 64 + tpb - 1) / tpb, tpb, 0, stream>>>(climber, Wc, bc, cemb, G * 64);
    k_cpre<<<4, tpb, 0, stream>>>(cemb, Wm1, bm1, cpre, G);
    k_final<<<bFin, tpb, 0, stream>>>(hbuf, cpre, batch, Wm1, Wm2, bm2, (float*)d_out, N);
}

// Round 7
// 558.872 us; speedup vs baseline: 2.2277x; 2.2277x over previous
//
#include <hip/hip_runtime.h>
#include <hip/hip_fp16.h>

#define SLOPE 0.2f
#define NEG_INF -3.4e38f

__device__ __forceinline__ float lrelu(float v) { return v >= 0.f ? v : SLOPE * v; }

__device__ __forceinline__ unsigned pack2(float a, float b) {
    __half2 h = __floats2half2_rn(a, b);
    return *reinterpret_cast<unsigned*>(&h);
}
__device__ __forceinline__ float4 h4tof4(uint2 u) {
    __half2 a = *reinterpret_cast<__half2*>(&u.x);
    __half2 b = *reinterpret_cast<__half2*>(&u.y);
    float2 fa = __half22float2(a), fb = __half22float2(b);
    return make_float4(fa.x, fa.y, fb.x, fb.y);
}

// ============================================================================
// xp = x @ W (K -> 128 = 2 heads * 64) + attention dots, block-tile GEMM.
// 64 nodes/block, 256 threads, micro-tile 4 nodes x 8 cols (32 accs -> no
// spill; VGPR_Count must stay < ~100, verify). Att dots via LDS f32 atomics.
// ============================================================================
template <int K>
__global__ __launch_bounds__(256)
void k_xp_gemm(const float* __restrict__ x, const float* __restrict__ W,
               const float* __restrict__ as_, const float* __restrict__ ad_,
               __half* __restrict__ xph, float* __restrict__ asrc,
               float* __restrict__ adst, int N) {
    constexpr int ZS = K + 1;                 // pad -> conflict-free z reads
    __shared__ float zs[64 * ZS];
    __shared__ float ws[K * 128];
    __shared__ float sh_ps[128];              // [node][head]
    __shared__ float sh_pd[128];
    const int n0 = blockIdx.x * 64;
    const int t = threadIdx.x;

    for (int i = t; i < K * 32; i += 256) ((float4*)ws)[i] = ((const float4*)W)[i];
    for (int i = t; i < 64 * K; i += 256) {
        int n = i / K, k = i - n * K;
        int gn = n0 + n;
        zs[n * ZS + k] = (gn < N) ? x[(size_t)gn * K + k] : 0.f;
    }
    if (t < 128) { sh_ps[t] = 0.f; sh_pd[t] = 0.f; }
    __syncthreads();

    const int tx = t & 15, ty = t >> 4;
    const int c0 = tx * 8;                    // global col (head = c0>>6)
    const int h = tx >> 3;

    float4 as0 = ((const float4*)(as_ + c0))[0];
    float4 as1 = ((const float4*)(as_ + c0))[1];
    float4 ad0 = ((const float4*)(ad_ + c0))[0];
    float4 ad1 = ((const float4*)(ad_ + c0))[1];

    float acc[4][8];
    #pragma unroll
    for (int i = 0; i < 4; ++i)
        #pragma unroll
        for (int j = 0; j < 8; ++j) acc[i][j] = 0.f;

    for (int k = 0; k < K; ++k) {
        float4 w0 = ((const float4*)(ws + k * 128 + c0))[0];
        float4 w1 = ((const float4*)(ws + k * 128 + c0))[1];
        #pragma unroll
        for (int i = 0; i < 4; ++i) {
            float zv = zs[(ty * 4 + i) * ZS + k];
            acc[i][0] += zv * w0.x; acc[i][1] += zv * w0.y;
            acc[i][2] += zv * w0.z; acc[i][3] += zv * w0.w;
            acc[i][4] += zv * w1.x; acc[i][5] += zv * w1.y;
            acc[i][6] += zv * w1.z; acc[i][7] += zv * w1.w;
        }
    }

    #pragma unroll
    for (int i = 0; i < 4; ++i) {
        int nl = ty * 4 + i, gn = n0 + nl;
        if (gn < N) {
            uint4 u;
            u.x = pack2(acc[i][0], acc[i][1]);
            u.y = pack2(acc[i][2], acc[i][3]);
            u.z = pack2(acc[i][4], acc[i][5]);
            u.w = pack2(acc[i][6], acc[i][7]);
            *(uint4*)(xph + (size_t)gn * 128 + c0) = u;
            float ps = acc[i][0]*as0.x + acc[i][1]*as0.y + acc[i][2]*as0.z + acc[i][3]*as0.w
                     + acc[i][4]*as1.x + acc[i][5]*as1.y + acc[i][6]*as1.z + acc[i][7]*as1.w;
            float pd = acc[i][0]*ad0.x + acc[i][1]*ad0.y + acc[i][2]*ad0.z + acc[i][3]*ad0.w
                     + acc[i][4]*ad1.x + acc[i][5]*ad1.y + acc[i][6]*ad1.z + acc[i][7]*ad1.w;
            atomicAdd(&sh_ps[nl * 2 + h], ps);
            atomicAdd(&sh_pd[nl * 2 + h], pd);
        }
    }
    __syncthreads();
    if (t < 128) {
        int gn = n0 + (t >> 1);
        if (gn < N) asrc[gn * 2 + (t & 1)] = sh_ps[t];
    } else {
        int tt = t - 128;
        int gn = n0 + (tt >> 1);
        if (gn < N) adst[gn * 2 + (tt & 1)] = sh_pd[tt];
    }
}

// ============================================================================
// CSR build: histogram -> exclusive scan -> scatter (counting sort by dst)
// ============================================================================
__global__ void k_hist(const int* __restrict__ dst, int* __restrict__ deg, int E) {
    for (int e = blockIdx.x * blockDim.x + threadIdx.x; e < E; e += gridDim.x * blockDim.x)
        atomicAdd(&deg[dst[e]], 1);
}

__global__ void k_scan_partial(const int* __restrict__ deg, int* __restrict__ partial, int N) {
    int b = blockIdx.x, t = threadIdx.x;
    int base = b * 1024 + t * 4;
    int s = 0;
    for (int i = 0; i < 4; ++i) { int idx = base + i; if (idx < N) s += deg[idx]; }
    __shared__ int sh[256];
    sh[t] = s; __syncthreads();
    for (int off = 128; off > 0; off >>= 1) { if (t < off) sh[t] += sh[t + off]; __syncthreads(); }
    if (t == 0) partial[b] = sh[0];
}

__global__ void k_scan_partials(int* __restrict__ partial, int nb) {
    __shared__ int sh[256];
    __shared__ int carry;
    int t = threadIdx.x;
    if (t == 0) carry = 0;
    __syncthreads();
    for (int base = 0; base < nb; base += 256) {
        int idx = base + t;
        int orig = (idx < nb) ? partial[idx] : 0;
        sh[t] = orig; __syncthreads();
        for (int off = 1; off < 256; off <<= 1) {
            int v = (t >= off) ? sh[t - off] : 0;
            __syncthreads();
            sh[t] += v;
            __syncthreads();
        }
        if (idx < nb) partial[idx] = carry + sh[t] - orig;
        __syncthreads();
        if (t == 0) carry += sh[255];
        __syncthreads();
    }
}

__global__ void k_scan_final(const int* __restrict__ deg, const int* __restrict__ partial,
                             int* __restrict__ rowptr, int N, int E) {
    int b = blockIdx.x, t = threadIdx.x;
    int base = b * 1024 + t * 4;
    int local[4]; int s = 0;
    for (int i = 0; i < 4; ++i) { int idx = base + i; local[i] = (idx < N) ? deg[idx] : 0; s += local[i]; }
    __shared__ int sh[256];
    int orig = s;
    sh[t] = s; __syncthreads();
    for (int off = 1; off < 256; off <<= 1) {
        int v = (t >= off) ? sh[t - off] : 0;
        __syncthreads();
        sh[t] += v;
        __syncthreads();
    }
    int run = partial[b] + sh[t] - orig;
    for (int i = 0; i < 4; ++i) {
        int idx = base + i;
        if (idx < N) rowptr[idx] = run;
        run += local[i];
    }
    if (b == 0 && t == 0) rowptr[N] = E;
}

__global__ void k_scatter(const int* __restrict__ src, const int* __restrict__ dst,
                          const int* __restrict__ rowptr, int* __restrict__ cur,
                          int* __restrict__ csr_src, int E) {
    for (int e = blockIdx.x * blockDim.x + threadIdx.x; e < E; e += gridDim.x * blockDim.x) {
        int d = dst[e];
        int pos = atomicAdd(&cur[d], 1);
        csr_src[rowptr[d] + pos] = src[e];
    }
}

// ============================================================================
// Per-node softmax -> alpha planes. Persistent wave-pair per node (wave=head).
// ============================================================================
__global__ void k_node_alpha(const int* __restrict__ rowptr, const int* __restrict__ csr_src,
                             const float* __restrict__ asrc, const float* __restrict__ adst,
                             float* __restrict__ alpha, float* __restrict__ aself,
                             int N, int E) {
    int tid = blockIdx.x * blockDim.x + threadIdx.x;
    int lane = threadIdx.x & 63;
    int h = (threadIdx.x >> 6) & 1;
    int pair = tid >> 7;
    int npairs = (gridDim.x * blockDim.x) >> 7;

    for (int n = pair; n < N; n += npairs) {
        int rs = rowptr[n], re = rowptr[n + 1], cnt = re - rs;
        float a_dst = adst[n * 2 + h];
        float v_self = lrelu(asrc[n * 2 + h] + a_dst);

        if (cnt <= 64) {
            float v = NEG_INF;
            if (lane < cnt) {
                int s = csr_src[rs + lane];
                v = lrelu(asrc[s * 2 + h] + a_dst);
            }
            float m = fmaxf(v, v_self);
            for (int off = 32; off > 0; off >>= 1) m = fmaxf(m, __shfl_xor(m, off, 64));
            float ex = (lane < cnt) ? __expf(v - m) : 0.f;
            float exs = __expf(v_self - m);
            float den = ex + (lane == 0 ? exs : 0.f);
            for (int off = 32; off > 0; off >>= 1) den += __shfl_xor(den, off, 64);
            float inv = 1.f / (den + 1e-16f);
            if (lane < cnt) alpha[(size_t)h * E + rs + lane] = ex * inv;
            if (lane == 0) aself[(size_t)h * N + n] = exs * inv;
        } else {
            float m = v_self;
            for (int e = rs + lane; e < re; e += 64) {
                int s = csr_src[e];
                m = fmaxf(m, lrelu(asrc[s * 2 + h] + a_dst));
            }
            for (int off = 32; off > 0; off >>= 1) m = fmaxf(m, __shfl_xor(m, off, 64));
            float den = (lane == 0) ? __expf(v_self - m) : 0.f;
            for (int e = rs + lane; e < re; e += 64) {
                int s = csr_src[e];
                den += __expf(lrelu(asrc[s * 2 + h] + a_dst) - m);
            }
            for (int off = 32; off > 0; off >>= 1) den += __shfl_xor(den, off, 64);
            float inv = 1.f / (den + 1e-16f);
            for (int e = rs + lane; e < re; e += 64) {
                int s = csr_src[e];
                alpha[(size_t)h * E + e] = __expf(lrelu(asrc[s * 2 + h] + a_dst) - m) * inv;
            }
            if (lane == 0) aself[(size_t)h * N + n] = __expf(v_self - m) * inv;
        }
    }
}

// ============================================================================
// Weighted gather (fp16 xp): one wave per node, 4 lane-groups of 16:
// group g -> head (g&1), edge offset (g>>1). 2x unrolled. 8 B/lane loads.
// ============================================================================
__global__ void k_gather(const int* __restrict__ rowptr, const int* __restrict__ csr_src,
                         const float* __restrict__ alpha, const float* __restrict__ aself,
                         const __half* __restrict__ xph, const float* __restrict__ b,
                         float* __restrict__ hout, int N, int E) {
    int tid = blockIdx.x * blockDim.x + threadIdx.x;
    int lane = threadIdx.x & 63;
    int wid = tid >> 6;
    int nw = (gridDim.x * blockDim.x) >> 6;
    int g = lane >> 4, c4 = lane & 15;
    int h = g & 1, eo = g >> 1;
    const uint2* xp2 = (const uint2*)xph;   // row = 32 uint2 (16 per head)
    float4 bb = ((const float4*)b)[c4];

    for (int n = wid; n < N; n += nw) {
        int rs = rowptr[n], re = rowptr[n + 1];
        float4 acc = make_float4(0.f, 0.f, 0.f, 0.f);
        if (eo == 0) {
            float a0 = aself[(size_t)h * N + n];
            float4 v = h4tof4(xp2[(size_t)n * 32 + h * 16 + c4]);
            acc.x = a0 * v.x; acc.y = a0 * v.y; acc.z = a0 * v.z; acc.w = a0 * v.w;
        }
        for (int e0 = rs; e0 < re; e0 += 4) {
            int ea = e0 + eo, eb = e0 + 2 + eo;
            bool va = ea < re, vb = eb < re;
            int sa = va ? csr_src[ea] : n;
            int sb = vb ? csr_src[eb] : n;
            float aa = va ? alpha[(size_t)h * E + ea] : 0.f;
            float ab = vb ? alpha[(size_t)h * E + eb] : 0.f;
            float4 v1 = h4tof4(xp2[(size_t)sa * 32 + h * 16 + c4]);
            float4 v2 = h4tof4(xp2[(size_t)sb * 32 + h * 16 + c4]);
            acc.x += aa * v1.x + ab * v2.x;
            acc.y += aa * v1.y + ab * v2.y;
            acc.z += aa * v1.z + ab * v2.z;
            acc.w += aa * v1.w + ab * v2.w;
        }
        acc.x += __shfl_xor(acc.x, 32, 64);
        acc.y += __shfl_xor(acc.y, 32, 64);
        acc.z += __shfl_xor(acc.z, 32, 64);
        acc.w += __shfl_xor(acc.w, 32, 64);
        acc.x += __shfl_xor(acc.x, 16, 64);
        acc.y += __shfl_xor(acc.y, 16, 64);
        acc.z += __shfl_xor(acc.z, 16, 64);
        acc.w += __shfl_xor(acc.w, 16, 64);
        if (g == 0) {
            float4 r;
            r.x = fmaxf(acc.x * 0.5f + bb.x, 0.f);
            r.y = fmaxf(acc.y * 0.5f + bb.y, 0.f);
            r.z = fmaxf(acc.z * 0.5f + bb.z, 0.f);
            r.w = fmaxf(acc.w * 0.5f + bb.w, 0.f);
            ((float4*)hout)[(size_t)n * 16 + c4] = r;
        }
    }
}

// climber embed: relu(climber @ Wc + bc), [G,64]
__global__ void k_climber(const float* __restrict__ climber, const float* __restrict__ Wc,
                          const float* __restrict__ bc, float* __restrict__ cemb, int g64) {
    int i = blockIdx.x * blockDim.x + threadIdx.x;
    if (i >= g64) return;
    int g = i >> 6, c = i & 63;
    float acc = bc[c];
    for (int k = 0; k < 4; ++k) acc += climber[g * 4 + k] * Wc[k * 64 + c];
    cemb[i] = acc > 0.f ? acc : 0.f;
}

// cpre[g] = cemb[g] @ Wm1[64:128] + bm1  (scalar accumulator, no spill risk)
__global__ void k_cpre(const float* __restrict__ cemb, const float* __restrict__ Wm1,
                       const float* __restrict__ bm1, float* __restrict__ cpre, int G) {
    int i = blockIdx.x * blockDim.x + threadIdx.x;
    if (i >= G * 64) return;
    int g = i >> 6, c = i & 63;
    float acc = bm1[c];
    for (int k = 0; k < 64; ++k)
        acc += cemb[g * 64 + k] * Wm1[(64 + k) * 64 + c];
    cpre[i] = acc;
}

// ============================================================================
// Final MLP, block-tile GEMM: 64 nodes/block, 256 threads, 4x4 micro-tile.
// m = h2@Wm1_a + cpre[batch]; relu; x Wm2 via LDS-atomic reduction.
// ============================================================================
__global__ __launch_bounds__(256)
void k_final(const float* __restrict__ h2, const float* __restrict__ cpre,
             const int* __restrict__ batch, const float* __restrict__ Wm1,
             const float* __restrict__ Wm2, const float* __restrict__ bm2,
             float* __restrict__ out, int N) {
    __shared__ float zs[64 * 65];
    __shared__ float ws[64 * 64];
    __shared__ float4 w2l[64];
    __shared__ float sh_out[256];
    const int n0 = blockIdx.x * 64;
    const int t = threadIdx.x;

    for (int i = t; i < 1024; i += 256) ((float4*)ws)[i] = ((const float4*)Wm1)[i];
    if (t < 64) w2l[t] = ((const float4*)Wm2)[t];
    for (int i = t; i < 64 * 64; i += 256) {
        int n = i >> 6, k = i & 63;
        int gn = n0 + n;
        zs[n * 65 + k] = (gn < N) ? h2[(size_t)gn * 64 + k] : 0.f;
    }
    sh_out[t] = 0.f;
    __syncthreads();

    const int tx = t & 15, ty = t >> 4;
    const int c0 = tx * 4;
    float acc[4][4];
    #pragma unroll
    for (int i = 0; i < 4; ++i)
        #pragma unroll
        for (int j = 0; j < 4; ++j) acc[i][j] = 0.f;

    for (int k = 0; k < 64; ++k) {
        float4 wv = *(const float4*)(ws + k * 64 + c0);
        #pragma unroll
        for (int i = 0; i < 4; ++i) {
            float zv = zs[(ty * 4 + i) * 65 + k];
            acc[i][0] += zv * wv.x; acc[i][1] += zv * wv.y;
            acc[i][2] += zv * wv.z; acc[i][3] += zv * wv.w;
        }
    }

    float4 wa = w2l[c0], wb = w2l[c0 + 1], wc = w2l[c0 + 2], wd = w2l[c0 + 3];
    #pragma unroll
    for (int i = 0; i < 4; ++i) {
        int nl = ty * 4 + i, gn = n0 + nl;
        if (gn < N) {
            int b = batch[gn];
            float4 cp = *(const float4*)(cpre + (size_t)b * 64 + c0);
            float m0 = fmaxf(acc[i][0] + cp.x, 0.f);
            float m1 = fmaxf(acc[i][1] + cp.y, 0.f);
            float m2 = fmaxf(acc[i][2] + cp.z, 0.f);
            float m3 = fmaxf(acc[i][3] + cp.w, 0.f);
            float ox = m0 * wa.x + m1 * wb.x + m2 * wc.x + m3 * wd.x;
            float oy = m0 * wa.y + m1 * wb.y + m2 * wc.y + m3 * wd.y;
            float oz = m0 * wa.z + m1 * wb.z + m2 * wc.z + m3 * wd.z;
            float ow = m0 * wa.w + m1 * wb.w + m2 * wc.w + m3 * wd.w;
            atomicAdd(&sh_out[nl * 4 + 0], ox);
            atomicAdd(&sh_out[nl * 4 + 1], oy);
            atomicAdd(&sh_out[nl * 4 + 2], oz);
            atomicAdd(&sh_out[nl * 4 + 3], ow);
        }
    }
    __syncthreads();
    {
        int nl = t >> 2, j = t & 3, gn = n0 + nl;
        if (gn < N) out[(size_t)gn * 4 + j] = sh_out[t] + bm2[j];
    }
}

extern "C" void kernel_launch(void* const* d_in, const int* in_sizes, int n_in,
                              void* d_out, int out_size, void* d_ws, size_t ws_size,
                              hipStream_t stream) {
    const float* x       = (const float*)d_in[0];
    const int*   ei      = (const int*)  d_in[1];
    const int*   batch   = (const int*)  d_in[2];
    const float* climber = (const float*)d_in[3];
    const float* W1  = (const float*)d_in[4];
    const float* as1 = (const float*)d_in[5];
    const float* ad1 = (const float*)d_in[6];
    const float* b1  = (const float*)d_in[7];
    const float* W2  = (const float*)d_in[8];
    const float* as2 = (const float*)d_in[9];
    const float* ad2 = (const float*)d_in[10];
    const float* b2  = (const float*)d_in[11];
    const float* Wc  = (const float*)d_in[12];
    const float* bc  = (const float*)d_in[13];
    const float* Wm1 = (const float*)d_in[14];
    const float* bm1 = (const float*)d_in[15];
    const float* Wm2 = (const float*)d_in[16];
    const float* bm2 = (const float*)d_in[17];

    const int N  = in_sizes[0] / 6;
    const int E  = in_sizes[1] / 2;
    const int G  = in_sizes[3] / 4;

    const int* srcI = ei;
    const int* dstI = ei + E;

    // ---------------- workspace carve ----------------
    char* base = (char*)d_ws;
    size_t off = 0;
    auto carve = [&](size_t bytes) { void* p = base + off; off += (bytes + 255) & ~size_t(255); return p; };
    __half* xph   = (__half*)carve((size_t)N * 128 * 2);
    float* hbuf   = (float*)carve((size_t)N * 64 * 4);
    float* asrc   = (float*)carve((size_t)N * 2 * 4);
    float* adst   = (float*)carve((size_t)N * 2 * 4);
    float* cemb   = (float*)carve((size_t)G * 64 * 4);
    float* cpre   = (float*)carve((size_t)G * 64 * 4);
    int*   deg    = (int*)  carve((size_t)N * 4);
    int*   rowptr = (int*)  carve((size_t)(N + 1) * 4);
    int*   cur    = (int*)  carve((size_t)N * 4);
    int*   partial= (int*)  carve(4096 * 4);
    int*   csr_src= (int*)  carve((size_t)E * 4);
    float* alpha  = (float*)carve((size_t)E * 2 * 4);
    float* aself  = (float*)carve((size_t)N * 2 * 4);

    const int tpb = 256;
    const int nScanBlk = (N + 1023) / 1024;
    const int PG = 2048;                          // persistent grid for alpha/gather
    const int nTile = (N + 63) / 64;              // 64-node GEMM tiles

    // ---------------- CSR build (shared by both layers) ----------------
    hipMemsetAsync(deg, 0, (size_t)N * 4, stream);
    hipMemsetAsync(cur, 0, (size_t)N * 4, stream);
    k_hist<<<1024, tpb, 0, stream>>>(dstI, deg, E);
    k_scan_partial<<<nScanBlk, tpb, 0, stream>>>(deg, partial, N);
    k_scan_partials<<<1, tpb, 0, stream>>>(partial, nScanBlk);
    k_scan_final<<<nScanBlk, tpb, 0, stream>>>(deg, partial, rowptr, N, E);
    k_scatter<<<1024, tpb, 0, stream>>>(srcI, dstI, rowptr, cur, csr_src, E);

    // ---------------- layer 1 ----------------
    k_xp_gemm<6><<<nTile, tpb, 0, stream>>>(x, W1, as1, ad1, xph, asrc, adst, N);
    k_node_alpha<<<PG, tpb, 0, stream>>>(rowptr, csr_src, asrc, adst, alpha, aself, N, E);
    k_gather<<<PG, tpb, 0, stream>>>(rowptr, csr_src, alpha, aself, xph, b1, hbuf, N, E);

    // ---------------- layer 2 ----------------
    k_xp_gemm<64><<<nTile, tpb, 0, stream>>>(hbuf, W2, as2, ad2, xph, asrc, adst, N);
    k_node_alpha<<<PG, tpb, 0, stream>>>(rowptr, csr_src, asrc, adst, alpha, aself, N, E);
    k_gather<<<PG, tpb, 0, stream>>>(rowptr, csr_src, alpha, aself, xph, b2, hbuf, N, E);

    // ---------------- classifier ----------------
    k_climber<<<(G * 64 + tpb - 1) / tpb, tpb, 0, stream>>>(climber, Wc, bc, cemb, G * 64);
    k_cpre<<<(G * 64 + tpb - 1) / tpb, tpb, 0, stream>>>(cemb, Wm1, bm1, cpre, G);
    k_final<<<nTile, tpb, 0, stream>>>(hbuf, cpre, batch, Wm1, Wm2, bm2, (float*)d_out, N);
}

// Round 8
// 469.937 us; speedup vs baseline: 2.6493x; 1.1892x over previous
//
#include <hip/hip_runtime.h>
#include <hip/hip_fp16.h>

#define SLOPE 0.2f

__device__ __forceinline__ float lrelu(float v) { return v >= 0.f ? v : SLOPE * v; }

__device__ __forceinline__ unsigned pack2(float a, float b) {
    __half2 h = __floats2half2_rn(a, b);
    return *reinterpret_cast<unsigned*>(&h);
}
__device__ __forceinline__ float4 h4tof4(uint2 u) {
    __half2 a = *reinterpret_cast<__half2*>(&u.x);
    __half2 b = *reinterpret_cast<__half2*>(&u.y);
    float2 fa = __half22float2(a), fb = __half22float2(b);
    return make_float4(fa.x, fa.y, fb.x, fb.y);
}

// ============================================================================
// xp = x @ W (K -> 128 = 2 heads * 64) + attention dots, block-tile GEMM.
// 64 nodes/block, 256 threads, micro-tile 4 nodes x 8 cols (32 accs, no spill).
// Att dots reduced across the 8 tx-lanes of each head via shfl_xor (no LDS
// atomics -- R7's sh_ps atomics were 16-way same-address serialization).
// ============================================================================
template <int K>
__global__ __launch_bounds__(256)
void k_xp_gemm(const float* __restrict__ x, const float* __restrict__ W,
               const float* __restrict__ as_, const float* __restrict__ ad_,
               __half* __restrict__ xph, float* __restrict__ asrc,
               float* __restrict__ adst, int N) {
    constexpr int ZS = K + 1;
    __shared__ float zs[64 * ZS];
    __shared__ float ws[K * 128];
    const int n0 = blockIdx.x * 64;
    const int t = threadIdx.x;

    for (int i = t; i < K * 32; i += 256) ((float4*)ws)[i] = ((const float4*)W)[i];
    for (int i = t; i < 64 * K; i += 256) {
        int n = i / K, k = i - n * K;
        int gn = n0 + n;
        zs[n * ZS + k] = (gn < N) ? x[(size_t)gn * K + k] : 0.f;
    }
    __syncthreads();

    const int tx = t & 15, ty = t >> 4;
    const int c0 = tx * 8;                    // head = tx>>3
    const int h = tx >> 3;

    float4 as0 = ((const float4*)(as_ + c0))[0];
    float4 as1 = ((const float4*)(as_ + c0))[1];
    float4 ad0 = ((const float4*)(ad_ + c0))[0];
    float4 ad1 = ((const float4*)(ad_ + c0))[1];

    float acc[4][8];
    #pragma unroll
    for (int i = 0; i < 4; ++i)
        #pragma unroll
        for (int j = 0; j < 8; ++j) acc[i][j] = 0.f;

    for (int k = 0; k < K; ++k) {
        float4 w0 = ((const float4*)(ws + k * 128 + c0))[0];
        float4 w1 = ((const float4*)(ws + k * 128 + c0))[1];
        #pragma unroll
        for (int i = 0; i < 4; ++i) {
            float zv = zs[(ty * 4 + i) * ZS + k];
            acc[i][0] += zv * w0.x; acc[i][1] += zv * w0.y;
            acc[i][2] += zv * w0.z; acc[i][3] += zv * w0.w;
            acc[i][4] += zv * w1.x; acc[i][5] += zv * w1.y;
            acc[i][6] += zv * w1.z; acc[i][7] += zv * w1.w;
        }
    }

    #pragma unroll
    for (int i = 0; i < 4; ++i) {
        int nl = ty * 4 + i, gn = n0 + nl;
        if (gn < N) {
            uint4 u;
            u.x = pack2(acc[i][0], acc[i][1]);
            u.y = pack2(acc[i][2], acc[i][3]);
            u.z = pack2(acc[i][4], acc[i][5]);
            u.w = pack2(acc[i][6], acc[i][7]);
            *(uint4*)(xph + (size_t)gn * 128 + c0) = u;
        }
        float ps = acc[i][0]*as0.x + acc[i][1]*as0.y + acc[i][2]*as0.z + acc[i][3]*as0.w
                 + acc[i][4]*as1.x + acc[i][5]*as1.y + acc[i][6]*as1.z + acc[i][7]*as1.w;
        float pd = acc[i][0]*ad0.x + acc[i][1]*ad0.y + acc[i][2]*ad0.z + acc[i][3]*ad0.w
                 + acc[i][4]*ad1.x + acc[i][5]*ad1.y + acc[i][6]*ad1.z + acc[i][7]*ad1.w;
        #pragma unroll
        for (int off = 1; off <= 4; off <<= 1) {
            ps += __shfl_xor(ps, off, 64);
            pd += __shfl_xor(pd, off, 64);
        }
        if ((tx & 7) == 0 && gn < N) {
            asrc[gn * 2 + h] = ps;
            adst[gn * 2 + h] = pd;
        }
    }
}

// ============================================================================
// CSR build: histogram -> exclusive scan -> scatter (counting sort by dst)
// ============================================================================
__global__ void k_hist(const int* __restrict__ dst, int* __restrict__ deg, int E) {
    for (int e = blockIdx.x * blockDim.x + threadIdx.x; e < E; e += gridDim.x * blockDim.x)
        atomicAdd(&deg[dst[e]], 1);
}

__global__ void k_scan_partial(const int* __restrict__ deg, int* __restrict__ partial, int N) {
    int b = blockIdx.x, t = threadIdx.x;
    int base = b * 1024 + t * 4;
    int s = 0;
    for (int i = 0; i < 4; ++i) { int idx = base + i; if (idx < N) s += deg[idx]; }
    __shared__ int sh[256];
    sh[t] = s; __syncthreads();
    for (int off = 128; off > 0; off >>= 1) { if (t < off) sh[t] += sh[t + off]; __syncthreads(); }
    if (t == 0) partial[b] = sh[0];
}

__global__ void k_scan_partials(int* __restrict__ partial, int nb) {
    __shared__ int sh[256];
    __shared__ int carry;
    int t = threadIdx.x;
    if (t == 0) carry = 0;
    __syncthreads();
    for (int base = 0; base < nb; base += 256) {
        int idx = base + t;
        int orig = (idx < nb) ? partial[idx] : 0;
        sh[t] = orig; __syncthreads();
        for (int off = 1; off < 256; off <<= 1) {
            int v = (t >= off) ? sh[t - off] : 0;
            __syncthreads();
            sh[t] += v;
            __syncthreads();
        }
        if (idx < nb) partial[idx] = carry + sh[t] - orig;
        __syncthreads();
        if (t == 0) carry += sh[255];
        __syncthreads();
    }
}

__global__ void k_scan_final(const int* __restrict__ deg, const int* __restrict__ partial,
                             int* __restrict__ rowptr, int N, int E) {
    int b = blockIdx.x, t = threadIdx.x;
    int base = b * 1024 + t * 4;
    int local[4]; int s = 0;
    for (int i = 0; i < 4; ++i) { int idx = base + i; local[i] = (idx < N) ? deg[idx] : 0; s += local[i]; }
    __shared__ int sh[256];
    int orig = s;
    sh[t] = s; __syncthreads();
    for (int off = 1; off < 256; off <<= 1) {
        int v = (t >= off) ? sh[t - off] : 0;
        __syncthreads();
        sh[t] += v;
        __syncthreads();
    }
    int run = partial[b] + sh[t] - orig;
    for (int i = 0; i < 4; ++i) {
        int idx = base + i;
        if (idx < N) rowptr[idx] = run;
        run += local[i];
    }
    if (b == 0 && t == 0) rowptr[N] = E;
}

__global__ void k_scatter(const int* __restrict__ src, const int* __restrict__ dst,
                          const int* __restrict__ rowptr, int* __restrict__ cur,
                          int* __restrict__ csr_src, int E) {
    for (int e = blockIdx.x * blockDim.x + threadIdx.x; e < E; e += gridDim.x * blockDim.x) {
        int d = dst[e];
        int pos = atomicAdd(&cur[d], 1);
        csr_src[rowptr[d] + pos] = src[e];
    }
}

// ============================================================================
// FUSED softmax + gather: one wave per node.
// Phase 1: half-wave per head (32 lanes stride edges) -> max, den (butterfly).
// Phase 2: 4 groups of 16 (g>>1 = head matches lane>>5; g&1 = edge offset),
// alpha recomputed inline (exp is 1 VALU op; asrc re-read is L1-hot).
// ============================================================================
__global__ void k_ag(const int* __restrict__ rowptr, const int* __restrict__ csr_src,
                     const float* __restrict__ asrc, const float* __restrict__ adst,
                     const __half* __restrict__ xph, const float* __restrict__ b,
                     float* __restrict__ hout, int N) {
    int tid = blockIdx.x * blockDim.x + threadIdx.x;
    int lane = threadIdx.x & 63;
    int wid = tid >> 6;
    int nw = (gridDim.x * blockDim.x) >> 6;
    int l = lane & 31, hh = lane >> 5;        // phase-1 mapping (half = head)
    int g = lane >> 4, c4 = lane & 15;
    int eo = g & 1;                            // phase-2: head = g>>1 == hh
    const uint2* xp2 = (const uint2*)xph;
    float4 bb = ((const float4*)b)[c4];

    for (int n = wid; n < N; n += nw) {
        int rs = rowptr[n], re = rowptr[n + 1];
        float a_dst = adst[n * 2 + hh];
        float vself = lrelu(asrc[n * 2 + hh] + a_dst);

        // ---- phase 1: max & den per head ----
        float m = vself;
        for (int e = rs + l; e < re; e += 32)
            m = fmaxf(m, lrelu(asrc[csr_src[e] * 2 + hh] + a_dst));
        #pragma unroll
        for (int off = 16; off > 0; off >>= 1) m = fmaxf(m, __shfl_xor(m, off, 64));
        float den = (l == 0) ? __expf(vself - m) : 0.f;
        for (int e = rs + l; e < re; e += 32)
            den += __expf(lrelu(asrc[csr_src[e] * 2 + hh] + a_dst) - m);
        #pragma unroll
        for (int off = 16; off > 0; off >>= 1) den += __shfl_xor(den, off, 64);
        float inv = 1.f / (den + 1e-16f);

        // ---- phase 2: weighted gather, alpha inline ----
        float4 acc = make_float4(0.f, 0.f, 0.f, 0.f);
        if (eo == 0) {
            float a0 = __expf(vself - m) * inv;
            float4 v = h4tof4(xp2[(size_t)n * 32 + hh * 16 + c4]);
            acc.x = a0 * v.x; acc.y = a0 * v.y; acc.z = a0 * v.z; acc.w = a0 * v.w;
        }
        for (int e0 = rs; e0 < re; e0 += 4) {
            int ea = e0 + eo, eb = e0 + 2 + eo;
            bool va = ea < re, vb = eb < re;
            int sa = va ? csr_src[ea] : n;
            int sb = vb ? csr_src[eb] : n;
            float aa = va ? __expf(lrelu(asrc[sa * 2 + hh] + a_dst) - m) * inv : 0.f;
            float ab = vb ? __expf(lrelu(asrc[sb * 2 + hh] + a_dst) - m) * inv : 0.f;
            float4 v1 = h4tof4(xp2[(size_t)sa * 32 + hh * 16 + c4]);
            float4 v2 = h4tof4(xp2[(size_t)sb * 32 + hh * 16 + c4]);
            acc.x += aa * v1.x + ab * v2.x;
            acc.y += aa * v1.y + ab * v2.y;
            acc.z += aa * v1.z + ab * v2.z;
            acc.w += aa * v1.w + ab * v2.w;
        }
        // combine edge-offset groups (xor 16, within head), then heads (xor 32)
        acc.x += __shfl_xor(acc.x, 16, 64);
        acc.y += __shfl_xor(acc.y, 16, 64);
        acc.z += __shfl_xor(acc.z, 16, 64);
        acc.w += __shfl_xor(acc.w, 16, 64);
        acc.x += __shfl_xor(acc.x, 32, 64);
        acc.y += __shfl_xor(acc.y, 32, 64);
        acc.z += __shfl_xor(acc.z, 32, 64);
        acc.w += __shfl_xor(acc.w, 32, 64);
        if (g == 0) {
            float4 r;
            r.x = fmaxf(acc.x * 0.5f + bb.x, 0.f);
            r.y = fmaxf(acc.y * 0.5f + bb.y, 0.f);
            r.z = fmaxf(acc.z * 0.5f + bb.z, 0.f);
            r.w = fmaxf(acc.w * 0.5f + bb.w, 0.f);
            ((float4*)hout)[(size_t)n * 16 + c4] = r;
        }
    }
}

// ============================================================================
// climber embed + cpre fused: cpre[g] = relu(climber@Wc+bc) @ Wm1[64:128] + bm1
// block = 4 graphs x 64 ch.
// ============================================================================
__global__ __launch_bounds__(256)
void k_climber_cpre(const float* __restrict__ climber, const float* __restrict__ Wc,
                    const float* __restrict__ bc, const float* __restrict__ Wm1,
                    const float* __restrict__ bm1, float* __restrict__ cpre, int G) {
    __shared__ float ce[4][64];
    __shared__ float wm1b[64 * 64];
    int t = threadIdx.x;
    for (int i = t; i < 1024; i += 256) ((float4*)wm1b)[i] = ((const float4*)Wm1)[1024 + i];
    int gl = t >> 6, c = t & 63;
    int g = blockIdx.x * 4 + gl;
    float acc = bc[c];
    if (g < G)
        for (int k = 0; k < 4; ++k) acc += climber[g * 4 + k] * Wc[k * 64 + c];
    ce[gl][c] = fmaxf(acc, 0.f);
    __syncthreads();
    float o = bm1[c];
    for (int k = 0; k < 64; ++k) o += ce[gl][k] * wm1b[k * 64 + c];
    if (g < G) cpre[(size_t)g * 64 + c] = o;
}

// ============================================================================
// Final MLP, block-tile GEMM: 64 nodes/block, 256 threads, 4x4 micro-tile.
// Epilogue: per-thread partials -> reused zs LDS (stride 260, exact fit) ->
// 16-way sum per (node,out). No LDS atomics (R7's were 16-way serialized).
// ============================================================================
__global__ __launch_bounds__(256)
void k_final(const float* __restrict__ h2, const float* __restrict__ cpre,
             const int* __restrict__ batch, const float* __restrict__ Wm1,
             const float* __restrict__ Wm2, const float* __restrict__ bm2,
             float* __restrict__ out, int N) {
    __shared__ float zs[64 * 65];             // reused as 16x260 partial buffer
    __shared__ float ws[64 * 64];
    __shared__ float4 w2l[64];
    const int n0 = blockIdx.x * 64;
    const int t = threadIdx.x;

    for (int i = t; i < 1024; i += 256) ((float4*)ws)[i] = ((const float4*)Wm1)[i];
    if (t < 64) w2l[t] = ((const float4*)Wm2)[t];
    for (int i = t; i < 64 * 64; i += 256) {
        int n = i >> 6, k = i & 63;
        int gn = n0 + n;
        zs[n * 65 + k] = (gn < N) ? h2[(size_t)gn * 64 + k] : 0.f;
    }
    __syncthreads();

    const int tx = t & 15, ty = t >> 4;
    const int c0 = tx * 4;
    float acc[4][4];
    #pragma unroll
    for (int i = 0; i < 4; ++i)
        #pragma unroll
        for (int j = 0; j < 4; ++j) acc[i][j] = 0.f;

    for (int k = 0; k < 64; ++k) {
        float4 wv = *(const float4*)(ws + k * 64 + c0);
        #pragma unroll
        for (int i = 0; i < 4; ++i) {
            float zv = zs[(ty * 4 + i) * 65 + k];
            acc[i][0] += zv * wv.x; acc[i][1] += zv * wv.y;
            acc[i][2] += zv * wv.z; acc[i][3] += zv * wv.w;
        }
    }
    __syncthreads();                          // all zs reads done; reuse as partials

    float4 wa = w2l[c0], wb = w2l[c0 + 1], wc = w2l[c0 + 2], wd = w2l[c0 + 3];
    #pragma unroll
    for (int i = 0; i < 4; ++i) {
        int nl = ty * 4 + i, gn = n0 + nl;
        float4 o = make_float4(0.f, 0.f, 0.f, 0.f);
        if (gn < N) {
            int b = batch[gn];
            float4 cp = *(const float4*)(cpre + (size_t)b * 64 + c0);
            float m0 = fmaxf(acc[i][0] + cp.x, 0.f);
            float m1 = fmaxf(acc[i][1] + cp.y, 0.f);
            float m2 = fmaxf(acc[i][2] + cp.z, 0.f);
            float m3 = fmaxf(acc[i][3] + cp.w, 0.f);
            o.x = m0 * wa.x + m1 * wb.x + m2 * wc.x + m3 * wd.x;
            o.y = m0 * wa.y + m1 * wb.y + m2 * wc.y + m3 * wd.y;
            o.z = m0 * wa.z + m1 * wb.z + m2 * wc.z + m3 * wd.z;
            o.w = m0 * wa.w + m1 * wb.w + m2 * wc.w + m3 * wd.w;
        }
        *(float4*)(zs + tx * 260 + nl * 4) = o;   // exclusive slot, no atomics
    }
    __syncthreads();
    {
        int nl = t >> 2, j = t & 3, gn = n0 + nl;
        float s = 0.f;
        #pragma unroll
        for (int tx2 = 0; tx2 < 16; ++tx2) s += zs[tx2 * 260 + nl * 4 + j];
        if (gn < N) out[(size_t)gn * 4 + j] = s + bm2[j];
    }
}

extern "C" void kernel_launch(void* const* d_in, const int* in_sizes, int n_in,
                              void* d_out, int out_size, void* d_ws, size_t ws_size,
                              hipStream_t stream) {
    const float* x       = (const float*)d_in[0];
    const int*   ei      = (const int*)  d_in[1];
    const int*   batch   = (const int*)  d_in[2];
    const float* climber = (const float*)d_in[3];
    const float* W1  = (const float*)d_in[4];
    const float* as1 = (const float*)d_in[5];
    const float* ad1 = (const float*)d_in[6];
    const float* b1  = (const float*)d_in[7];
    const float* W2  = (const float*)d_in[8];
    const float* as2 = (const float*)d_in[9];
    const float* ad2 = (const float*)d_in[10];
    const float* b2  = (const float*)d_in[11];
    const float* Wc  = (const float*)d_in[12];
    const float* bc  = (const float*)d_in[13];
    const float* Wm1 = (const float*)d_in[14];
    const float* bm1 = (const float*)d_in[15];
    const float* Wm2 = (const float*)d_in[16];
    const float* bm2 = (const float*)d_in[17];

    const int N  = in_sizes[0] / 6;
    const int E  = in_sizes[1] / 2;
    const int G  = in_sizes[3] / 4;

    const int* srcI = ei;
    const int* dstI = ei + E;

    // ---------------- workspace carve ----------------
    char* base = (char*)d_ws;
    size_t off = 0;
    auto carve = [&](size_t bytes) { void* p = base + off; off += (bytes + 255) & ~size_t(255); return p; };
    __half* xph   = (__half*)carve((size_t)N * 128 * 2);
    float* hbuf   = (float*)carve((size_t)N * 64 * 4);
    float* asrc   = (float*)carve((size_t)N * 2 * 4);
    float* adst   = (float*)carve((size_t)N * 2 * 4);
    float* cpre   = (float*)carve((size_t)G * 64 * 4);
    int*   deg    = (int*)  carve((size_t)N * 4);
    int*   rowptr = (int*)  carve((size_t)(N + 1) * 4);
    int*   cur    = (int*)  carve((size_t)N * 4);
    int*   partial= (int*)  carve(4096 * 4);
    int*   csr_src= (int*)  carve((size_t)E * 4);

    const int tpb = 256;
    const int nScanBlk = (N + 1023) / 1024;
    const int PG = 2048;                          // persistent grid for k_ag
    const int nTile = (N + 63) / 64;

    // ---------------- CSR build (shared by both layers) ----------------
    hipMemsetAsync(deg, 0, (size_t)N * 4, stream);
    hipMemsetAsync(cur, 0, (size_t)N * 4, stream);
    k_hist<<<1024, tpb, 0, stream>>>(dstI, deg, E);
    k_scan_partial<<<nScanBlk, tpb, 0, stream>>>(deg, partial, N);
    k_scan_partials<<<1, tpb, 0, stream>>>(partial, nScanBlk);
    k_scan_final<<<nScanBlk, tpb, 0, stream>>>(deg, partial, rowptr, N, E);
    k_scatter<<<1024, tpb, 0, stream>>>(srcI, dstI, rowptr, cur, csr_src, E);

    // ---------------- layer 1 ----------------
    k_xp_gemm<6><<<nTile, tpb, 0, stream>>>(x, W1, as1, ad1, xph, asrc, adst, N);
    k_ag<<<PG, tpb, 0, stream>>>(rowptr, csr_src, asrc, adst, xph, b1, hbuf, N);

    // ---------------- layer 2 ----------------
    k_xp_gemm<64><<<nTile, tpb, 0, stream>>>(hbuf, W2, as2, ad2, xph, asrc, adst, N);
    k_ag<<<PG, tpb, 0, stream>>>(rowptr, csr_src, asrc, adst, xph, b2, hbuf, N);

    // ---------------- classifier ----------------
    k_climber_cpre<<<(G + 3) / 4, tpb, 0, stream>>>(climber, Wc, bc, Wm1, bm1, cpre, G);
    k_final<<<nTile, tpb, 0, stream>>>(hbuf, cpre, batch, Wm1, Wm2, bm2, (float*)d_out, N);
}

// Round 9
// 382.518 us; speedup vs baseline: 3.2548x; 1.2285x over previous
//
#include <hip/hip_runtime.h>
#include <hip/hip_fp16.h>

#define SLOPE 0.2f

__device__ __forceinline__ float lrelu(float v) { return v >= 0.f ? v : SLOPE * v; }

__device__ __forceinline__ unsigned pack2(float a, float b) {
    __half2 h = __floats2half2_rn(a, b);
    return *reinterpret_cast<unsigned*>(&h);
}
__device__ __forceinline__ float4 h4tof4(uint2 u) {
    __half2 a = *reinterpret_cast<__half2*>(&u.x);
    __half2 b = *reinterpret_cast<__half2*>(&u.y);
    float2 fa = __half22float2(a), fb = __half22float2(b);
    return make_float4(fa.x, fa.y, fb.x, fb.y);
}
__device__ __forceinline__ void acc8(float4& A, float4& B, float a, uint4 u) {
    float4 lo = h4tof4(make_uint2(u.x, u.y));
    float4 hi = h4tof4(make_uint2(u.z, u.w));
    A.x += a * lo.x; A.y += a * lo.y; A.z += a * lo.z; A.w += a * lo.w;
    B.x += a * hi.x; B.y += a * hi.y; B.z += a * hi.z; B.w += a * hi.w;
}

// ============================================================================
// xp = x @ W (K -> 128 = 2 heads * 64) + attention dots, block-tile GEMM.
// 64 nodes/block, 256 threads, micro-tile 4 nodes x 8 cols (32 accs, no spill).
// ============================================================================
template <int K>
__global__ __launch_bounds__(256)
void k_xp_gemm(const float* __restrict__ x, const float* __restrict__ W,
               const float* __restrict__ as_, const float* __restrict__ ad_,
               __half* __restrict__ xph, float* __restrict__ asrc,
               float* __restrict__ adst, int N) {
    constexpr int ZS = K + 1;
    __shared__ float zs[64 * ZS];
    __shared__ float ws[K * 128];
    const int n0 = blockIdx.x * 64;
    const int t = threadIdx.x;

    for (int i = t; i < K * 32; i += 256) ((float4*)ws)[i] = ((const float4*)W)[i];
    for (int i = t; i < 64 * K; i += 256) {
        int n = i / K, k = i - n * K;
        int gn = n0 + n;
        zs[n * ZS + k] = (gn < N) ? x[(size_t)gn * K + k] : 0.f;
    }
    __syncthreads();

    const int tx = t & 15, ty = t >> 4;
    const int c0 = tx * 8;
    const int h = tx >> 3;

    float4 as0 = ((const float4*)(as_ + c0))[0];
    float4 as1 = ((const float4*)(as_ + c0))[1];
    float4 ad0 = ((const float4*)(ad_ + c0))[0];
    float4 ad1 = ((const float4*)(ad_ + c0))[1];

    float acc[4][8];
    #pragma unroll
    for (int i = 0; i < 4; ++i)
        #pragma unroll
        for (int j = 0; j < 8; ++j) acc[i][j] = 0.f;

    for (int k = 0; k < K; ++k) {
        float4 w0 = ((const float4*)(ws + k * 128 + c0))[0];
        float4 w1 = ((const float4*)(ws + k * 128 + c0))[1];
        #pragma unroll
        for (int i = 0; i < 4; ++i) {
            float zv = zs[(ty * 4 + i) * ZS + k];
            acc[i][0] += zv * w0.x; acc[i][1] += zv * w0.y;
            acc[i][2] += zv * w0.z; acc[i][3] += zv * w0.w;
            acc[i][4] += zv * w1.x; acc[i][5] += zv * w1.y;
            acc[i][6] += zv * w1.z; acc[i][7] += zv * w1.w;
        }
    }

    #pragma unroll
    for (int i = 0; i < 4; ++i) {
        int nl = ty * 4 + i, gn = n0 + nl;
        if (gn < N) {
            uint4 u;
            u.x = pack2(acc[i][0], acc[i][1]);
            u.y = pack2(acc[i][2], acc[i][3]);
            u.z = pack2(acc[i][4], acc[i][5]);
            u.w = pack2(acc[i][6], acc[i][7]);
            *(uint4*)(xph + (size_t)gn * 128 + c0) = u;
        }
        float ps = acc[i][0]*as0.x + acc[i][1]*as0.y + acc[i][2]*as0.z + acc[i][3]*as0.w
                 + acc[i][4]*as1.x + acc[i][5]*as1.y + acc[i][6]*as1.z + acc[i][7]*as1.w;
        float pd = acc[i][0]*ad0.x + acc[i][1]*ad0.y + acc[i][2]*ad0.z + acc[i][3]*ad0.w
                 + acc[i][4]*ad1.x + acc[i][5]*ad1.y + acc[i][6]*ad1.z + acc[i][7]*ad1.w;
        #pragma unroll
        for (int off = 1; off <= 4; off <<= 1) {
            ps += __shfl_xor(ps, off, 64);
            pd += __shfl_xor(pd, off, 64);
        }
        if ((tx & 7) == 0 && gn < N) {
            asrc[gn * 2 + h] = ps;
            adst[gn * 2 + h] = pd;
        }
    }
}

// ============================================================================
// CSR build: histogram -> exclusive scan -> scatter (counting sort by dst)
// ============================================================================
__global__ void k_hist(const int* __restrict__ dst, int* __restrict__ deg, int E) {
    for (int e = blockIdx.x * blockDim.x + threadIdx.x; e < E; e += gridDim.x * blockDim.x)
        atomicAdd(&deg[dst[e]], 1);
}

__global__ void k_scan_partial(const int* __restrict__ deg, int* __restrict__ partial, int N) {
    int b = blockIdx.x, t = threadIdx.x;
    int base = b * 1024 + t * 4;
    int s = 0;
    for (int i = 0; i < 4; ++i) { int idx = base + i; if (idx < N) s += deg[idx]; }
    __shared__ int sh[256];
    sh[t] = s; __syncthreads();
    for (int off = 128; off > 0; off >>= 1) { if (t < off) sh[t] += sh[t + off]; __syncthreads(); }
    if (t == 0) partial[b] = sh[0];
}

__global__ void k_scan_partials(int* __restrict__ partial, int nb) {
    __shared__ int sh[256];
    __shared__ int carry;
    int t = threadIdx.x;
    if (t == 0) carry = 0;
    __syncthreads();
    for (int base = 0; base < nb; base += 256) {
        int idx = base + t;
        int orig = (idx < nb) ? partial[idx] : 0;
        sh[t] = orig; __syncthreads();
        for (int off = 1; off < 256; off <<= 1) {
            int v = (t >= off) ? sh[t - off] : 0;
            __syncthreads();
            sh[t] += v;
            __syncthreads();
        }
        if (idx < nb) partial[idx] = carry + sh[t] - orig;
        __syncthreads();
        if (t == 0) carry += sh[255];
        __syncthreads();
    }
}

__global__ void k_scan_final(const int* __restrict__ deg, const int* __restrict__ partial,
                             int* __restrict__ rowptr, int N, int E) {
    int b = blockIdx.x, t = threadIdx.x;
    int base = b * 1024 + t * 4;
    int local[4]; int s = 0;
    for (int i = 0; i < 4; ++i) { int idx = base + i; local[i] = (idx < N) ? deg[idx] : 0; s += local[i]; }
    __shared__ int sh[256];
    int orig = s;
    sh[t] = s; __syncthreads();
    for (int off = 1; off < 256; off <<= 1) {
        int v = (t >= off) ? sh[t - off] : 0;
        __syncthreads();
        sh[t] += v;
        __syncthreads();
    }
    int run = partial[b] + sh[t] - orig;
    for (int i = 0; i < 4; ++i) {
        int idx = base + i;
        if (idx < N) rowptr[idx] = run;
        run += local[i];
    }
    if (b == 0 && t == 0) rowptr[N] = E;
}

__global__ void k_scatter(const int* __restrict__ src, const int* __restrict__ dst,
                          const int* __restrict__ rowptr, int* __restrict__ cur,
                          int* __restrict__ csr_src, int E) {
    for (int e = blockIdx.x * blockDim.x + threadIdx.x; e < E; e += gridDim.x * blockDim.x) {
        int d = dst[e];
        int pos = atomicAdd(&cur[d], 1);
        csr_src[rowptr[d] + pos] = src[e];
    }
}

// ============================================================================
// FUSED softmax + gather, v2. One wave per node.
// - No max-subtraction: logits are O(+-5) here (normalized inputs, 1/sqrt(d)
//   weights); exp() can't overflow fp32. Mathematically identical softmax.
// - Phase 1 (single pass): lane l<32 = head-0 edge slots, lanes 32-63 head 1.
//   Each lane computes its edge's exp once, keeps it + src id in registers.
// - Phase 2: 8 groups of 8 lanes (head = lane>>5, edge offset = (lane>>3)&3);
//   alpha & src broadcast from phase-1 registers via shfl; 16 B xp gathers,
//   8 edges/head in flight. deg>32 fallback recomputes inline (P ~ 4e-9).
// ============================================================================
__global__ void k_ag(const int* __restrict__ rowptr, const int* __restrict__ csr_src,
                     const float* __restrict__ asrc, const float* __restrict__ adst,
                     const __half* __restrict__ xph, const float* __restrict__ b,
                     float* __restrict__ hout, int N) {
    int tid = blockIdx.x * blockDim.x + threadIdx.x;
    int lane = threadIdx.x & 63;
    int wid = tid >> 6;
    int nw = (gridDim.x * blockDim.x) >> 6;
    const int l  = lane & 31;          // phase-1 edge slot within head
    const int hh = lane >> 5;          // head (both phases)
    const int g8 = (lane >> 3) & 3;    // phase-2 edge-offset group
    const int c8 = lane & 7;           // 8-channel quad index
    const uint4* xp4 = (const uint4*)xph;   // node row = 16 uint4 (8/head)
    float4 bb0 = ((const float4*)b)[c8 * 2];
    float4 bb1 = ((const float4*)b)[c8 * 2 + 1];

    for (int n = wid; n < N; n += nw) {
        int rs = rowptr[n], re = rowptr[n + 1], cnt = re - rs;
        float a_dst = adst[n * 2 + hh];
        float eself = __expf(lrelu(asrc[n * 2 + hh] + a_dst));

        float4 accA = make_float4(0.f, 0.f, 0.f, 0.f);
        float4 accB = make_float4(0.f, 0.f, 0.f, 0.f);

        if (cnt <= 32) {
            // ---- phase 1: one pass, exp kept in registers ----
            float ev = 0.f; int s_reg = n;
            if (l < cnt) {
                s_reg = csr_src[rs + l];
                ev = __expf(lrelu(asrc[s_reg * 2 + hh] + a_dst));
            }
            float den = ev + (l == 0 ? eself : 0.f);
            #pragma unroll
            for (int off = 16; off > 0; off >>= 1) den += __shfl_xor(den, off, 64);
            float inv = 1.f / (den + 1e-16f);
            float alpha_l = ev * inv;

            // ---- phase 2: gather, alpha via shfl broadcast ----
            if (g8 == 0) acc8(accA, accB, eself * inv, xp4[(size_t)n * 16 + hh * 8 + c8]);
            int base = (hh << 5) - rs;
            for (int e0 = rs; e0 < re; e0 += 8) {
                int ea = e0 + g8, eb = e0 + 4 + g8;
                bool va = ea < re, vb = eb < re;
                float aa = __shfl(alpha_l, base + ea, 64);
                int   sa = __shfl(s_reg,   base + ea, 64);
                float ab = __shfl(alpha_l, base + eb, 64);
                int   sb = __shfl(s_reg,   base + eb, 64);
                if (!va) { aa = 0.f; sa = n; }
                if (!vb) { ab = 0.f; sb = n; }
                uint4 u1 = xp4[(size_t)sa * 16 + hh * 8 + c8];
                uint4 u2 = xp4[(size_t)sb * 16 + hh * 8 + c8];
                acc8(accA, accB, aa, u1);
                acc8(accA, accB, ab, u2);
            }
        } else {
            // ---- rare slow path (deg > 32) ----
            float den = (l == 0) ? eself : 0.f;
            for (int e = rs + l; e < re; e += 32)
                den += __expf(lrelu(asrc[csr_src[e] * 2 + hh] + a_dst));
            #pragma unroll
            for (int off = 16; off > 0; off >>= 1) den += __shfl_xor(den, off, 64);
            float inv = 1.f / (den + 1e-16f);
            if (g8 == 0) acc8(accA, accB, eself * inv, xp4[(size_t)n * 16 + hh * 8 + c8]);
            for (int e0 = rs; e0 < re; e0 += 8) {
                int ea = e0 + g8, eb = e0 + 4 + g8;
                bool va = ea < re, vb = eb < re;
                int sa = va ? csr_src[ea] : n;
                int sb = vb ? csr_src[eb] : n;
                float aa = va ? __expf(lrelu(asrc[sa * 2 + hh] + a_dst)) * inv : 0.f;
                float ab = vb ? __expf(lrelu(asrc[sb * 2 + hh] + a_dst)) * inv : 0.f;
                uint4 u1 = xp4[(size_t)sa * 16 + hh * 8 + c8];
                uint4 u2 = xp4[(size_t)sb * 16 + hh * 8 + c8];
                acc8(accA, accB, aa, u1);
                acc8(accA, accB, ab, u2);
            }
        }

        // combine edge-offset groups (xor 8, 16) then heads (xor 32)
        #pragma unroll
        for (int off = 8; off <= 32; off <<= 1) {
            accA.x += __shfl_xor(accA.x, off, 64);
            accA.y += __shfl_xor(accA.y, off, 64);
            accA.z += __shfl_xor(accA.z, off, 64);
            accA.w += __shfl_xor(accA.w, off, 64);
            accB.x += __shfl_xor(accB.x, off, 64);
            accB.y += __shfl_xor(accB.y, off, 64);
            accB.z += __shfl_xor(accB.z, off, 64);
            accB.w += __shfl_xor(accB.w, off, 64);
        }
        if (lane < 8) {
            float4 r0, r1;
            r0.x = fmaxf(accA.x * 0.5f + bb0.x, 0.f);
            r0.y = fmaxf(accA.y * 0.5f + bb0.y, 0.f);
            r0.z = fmaxf(accA.z * 0.5f + bb0.z, 0.f);
            r0.w = fmaxf(accA.w * 0.5f + bb0.w, 0.f);
            r1.x = fmaxf(accB.x * 0.5f + bb1.x, 0.f);
            r1.y = fmaxf(accB.y * 0.5f + bb1.y, 0.f);
            r1.z = fmaxf(accB.z * 0.5f + bb1.z, 0.f);
            r1.w = fmaxf(accB.w * 0.5f + bb1.w, 0.f);
            ((float4*)hout)[(size_t)n * 16 + c8 * 2]     = r0;
            ((float4*)hout)[(size_t)n * 16 + c8 * 2 + 1] = r1;
        }
    }
}

// ============================================================================
// climber embed + cpre fused: cpre[g] = relu(climber@Wc+bc) @ Wm1[64:128] + bm1
// ============================================================================
__global__ __launch_bounds__(256)
void k_climber_cpre(const float* __restrict__ climber, const float* __restrict__ Wc,
                    const float* __restrict__ bc, const float* __restrict__ Wm1,
                    const float* __restrict__ bm1, float* __restrict__ cpre, int G) {
    __shared__ float ce[4][64];
    __shared__ float wm1b[64 * 64];
    int t = threadIdx.x;
    for (int i = t; i < 1024; i += 256) ((float4*)wm1b)[i] = ((const float4*)Wm1)[1024 + i];
    int gl = t >> 6, c = t & 63;
    int g = blockIdx.x * 4 + gl;
    float acc = bc[c];
    if (g < G)
        for (int k = 0; k < 4; ++k) acc += climber[g * 4 + k] * Wc[k * 64 + c];
    ce[gl][c] = fmaxf(acc, 0.f);
    __syncthreads();
    float o = bm1[c];
    for (int k = 0; k < 64; ++k) o += ce[gl][k] * wm1b[k * 64 + c];
    if (g < G) cpre[(size_t)g * 64 + c] = o;
}

// ============================================================================
// Final MLP, block-tile GEMM: 64 nodes/block, 256 threads, 4x4 micro-tile.
// Epilogue: per-thread partials in reused zs LDS, 16-way sum (no atomics).
// ============================================================================
__global__ __launch_bounds__(256)
void k_final(const float* __restrict__ h2, const float* __restrict__ cpre,
             const int* __restrict__ batch, const float* __restrict__ Wm1,
             const float* __restrict__ Wm2, const float* __restrict__ bm2,
             float* __restrict__ out, int N) {
    __shared__ float zs[64 * 65];
    __shared__ float ws[64 * 64];
    __shared__ float4 w2l[64];
    const int n0 = blockIdx.x * 64;
    const int t = threadIdx.x;

    for (int i = t; i < 1024; i += 256) ((float4*)ws)[i] = ((const float4*)Wm1)[i];
    if (t < 64) w2l[t] = ((const float4*)Wm2)[t];
    for (int i = t; i < 64 * 64; i += 256) {
        int n = i >> 6, k = i & 63;
        int gn = n0 + n;
        zs[n * 65 + k] = (gn < N) ? h2[(size_t)gn * 64 + k] : 0.f;
    }
    __syncthreads();

    const int tx = t & 15, ty = t >> 4;
    const int c0 = tx * 4;
    float acc[4][4];
    #pragma unroll
    for (int i = 0; i < 4; ++i)
        #pragma unroll
        for (int j = 0; j < 4; ++j) acc[i][j] = 0.f;

    for (int k = 0; k < 64; ++k) {
        float4 wv = *(const float4*)(ws + k * 64 + c0);
        #pragma unroll
        for (int i = 0; i < 4; ++i) {
            float zv = zs[(ty * 4 + i) * 65 + k];
            acc[i][0] += zv * wv.x; acc[i][1] += zv * wv.y;
            acc[i][2] += zv * wv.z; acc[i][3] += zv * wv.w;
        }
    }
    __syncthreads();

    float4 wa = w2l[c0], wb = w2l[c0 + 1], wc = w2l[c0 + 2], wd = w2l[c0 + 3];
    #pragma unroll
    for (int i = 0; i < 4; ++i) {
        int nl = ty * 4 + i, gn = n0 + nl;
        float4 o = make_float4(0.f, 0.f, 0.f, 0.f);
        if (gn < N) {
            int b = batch[gn];
            float4 cp = *(const float4*)(cpre + (size_t)b * 64 + c0);
            float m0 = fmaxf(acc[i][0] + cp.x, 0.f);
            float m1 = fmaxf(acc[i][1] + cp.y, 0.f);
            float m2 = fmaxf(acc[i][2] + cp.z, 0.f);
            float m3 = fmaxf(acc[i][3] + cp.w, 0.f);
            o.x = m0 * wa.x + m1 * wb.x + m2 * wc.x + m3 * wd.x;
            o.y = m0 * wa.y + m1 * wb.y + m2 * wc.y + m3 * wd.y;
            o.z = m0 * wa.z + m1 * wb.z + m2 * wc.z + m3 * wd.z;
            o.w = m0 * wa.w + m1 * wb.w + m2 * wc.w + m3 * wd.w;
        }
        *(float4*)(zs + tx * 260 + nl * 4) = o;
    }
    __syncthreads();
    {
        int nl = t >> 2, j = t & 3, gn = n0 + nl;
        float s = 0.f;
        #pragma unroll
        for (int tx2 = 0; tx2 < 16; ++tx2) s += zs[tx2 * 260 + nl * 4 + j];
        if (gn < N) out[(size_t)gn * 4 + j] = s + bm2[j];
    }
}

extern "C" void kernel_launch(void* const* d_in, const int* in_sizes, int n_in,
                              void* d_out, int out_size, void* d_ws, size_t ws_size,
                              hipStream_t stream) {
    const float* x       = (const float*)d_in[0];
    const int*   ei      = (const int*)  d_in[1];
    const int*   batch   = (const int*)  d_in[2];
    const float* climber = (const float*)d_in[3];
    const float* W1  = (const float*)d_in[4];
    const float* as1 = (const float*)d_in[5];
    const float* ad1 = (const float*)d_in[6];
    const float* b1  = (const float*)d_in[7];
    const float* W2  = (const float*)d_in[8];
    const float* as2 = (const float*)d_in[9];
    const float* ad2 = (const float*)d_in[10];
    const float* b2  = (const float*)d_in[11];
    const float* Wc  = (const float*)d_in[12];
    const float* bc  = (const float*)d_in[13];
    const float* Wm1 = (const float*)d_in[14];
    const float* bm1 = (const float*)d_in[15];
    const float* Wm2 = (const float*)d_in[16];
    const float* bm2 = (const float*)d_in[17];

    const int N  = in_sizes[0] / 6;
    const int E  = in_sizes[1] / 2;
    const int G  = in_sizes[3] / 4;

    const int* srcI = ei;
    const int* dstI = ei + E;

    // ---------------- workspace carve ----------------
    char* base = (char*)d_ws;
    size_t off = 0;
    auto carve = [&](size_t bytes) { void* p = base + off; off += (bytes + 255) & ~size_t(255); return p; };
    __half* xph   = (__half*)carve((size_t)N * 128 * 2);
    float* hbuf   = (float*)carve((size_t)N * 64 * 4);
    float* asrc   = (float*)carve((size_t)N * 2 * 4);
    float* adst   = (float*)carve((size_t)N * 2 * 4);
    float* cpre   = (float*)carve((size_t)G * 64 * 4);
    int*   deg    = (int*)  carve((size_t)N * 4);
    int*   rowptr = (int*)  carve((size_t)(N + 1) * 4);
    int*   cur    = (int*)  carve((size_t)N * 4);
    int*   partial= (int*)  carve(4096 * 4);
    int*   csr_src= (int*)  carve((size_t)E * 4);

    const int tpb = 256;
    const int nScanBlk = (N + 1023) / 1024;
    const int PG = 2048;
    const int nTile = (N + 63) / 64;

    // ---------------- CSR build (shared by both layers) ----------------
    hipMemsetAsync(deg, 0, (size_t)N * 4, stream);
    hipMemsetAsync(cur, 0, (size_t)N * 4, stream);
    k_hist<<<1024, tpb, 0, stream>>>(dstI, deg, E);
    k_scan_partial<<<nScanBlk, tpb, 0, stream>>>(deg, partial, N);
    k_scan_partials<<<1, tpb, 0, stream>>>(partial, nScanBlk);
    k_scan_final<<<nScanBlk, tpb, 0, stream>>>(deg, partial, rowptr, N, E);
    k_scatter<<<1024, tpb, 0, stream>>>(srcI, dstI, rowptr, cur, csr_src, E);

    // ---------------- layer 1 ----------------
    k_xp_gemm<6><<<nTile, tpb, 0, stream>>>(x, W1, as1, ad1, xph, asrc, adst, N);
    k_ag<<<PG, tpb, 0, stream>>>(rowptr, csr_src, asrc, adst, xph, b1, hbuf, N);

    // ---------------- layer 2 ----------------
    k_xp_gemm<64><<<nTile, tpb, 0, stream>>>(hbuf, W2, as2, ad2, xph, asrc, adst, N);
    k_ag<<<PG, tpb, 0, stream>>>(rowptr, csr_src, asrc, adst, xph, b2, hbuf, N);

    // ---------------- classifier ----------------
    k_climber_cpre<<<(G + 3) / 4, tpb, 0, stream>>>(climber, Wc, bc, Wm1, bm1, cpre, G);
    k_final<<<nTile, tpb, 0, stream>>>(hbuf, cpre, batch, Wm1, Wm2, bm2, (float*)d_out, N);
}